// Round 1
// baseline (198.616 us; speedup 1.0000x reference)
//
#include <hip/hip_runtime.h>

// YOLO layer decode, MI355X.
// B=32, C=255=(5+80)*3, W=H=76.
// Outputs (concat flat in d_out): boxes (B,P,4), conf (B,P,80), scores (B,P)
// with P = W*H*3, p = (w*H+h)*3 + a.

#define NCLS 80
#define NA   3
#define BB   32
#define WW   76
#define HH   76
#define WH   (WW*HH)          // 5776
#define PP   (WH*NA)          // 17328

__global__ __launch_bounds__(256) void yolo_decode_kernel(
    const float* __restrict__ in,       // (B, 255, W, H)
    const float* __restrict__ anchors,  // (2, 3) flat: [d*3 + a]
    float* __restrict__ boxes,          // (B, P, 4)
    float* __restrict__ conf,           // (B, P, 80)
    float* __restrict__ scores)         // (B, P)
{
    int idx = blockIdx.x * 256 + threadIdx.x;   // idx = (b*NA + a)*WH + s
    int s  = idx % WH;
    int ba = idx / WH;
    int a  = ba % NA;
    int b  = ba / NA;
    int w  = s / HH;
    int h  = s % HH;

    const float* base = in + (size_t)(b * 255 + a * 85) * WH + s;

    float tx = base[0];
    float ty = base[WH];
    float tw = base[2 * WH];
    float th = base[3 * WH];
    float to = base[4 * WH];

    float sx = 1.0f / (1.0f + __expf(-tx));
    float sy = 1.0f / (1.0f + __expf(-ty));
    float bx = (sx + (float)w) * (1.0f / WW);
    float by = (sy + (float)h) * (1.0f / HH);
    float bw = __expf(tw) * anchors[a];
    float bh = __expf(th) * anchors[3 + a];

    int p = s * 3 + a;

    float4 box = make_float4(bx - 0.5f * bw, by - 0.5f * bh,
                             bx + 0.5f * bw, by + 0.5f * bh);
    *reinterpret_cast<float4*>(boxes + (size_t)(b * PP + p) * 4) = box;

    float so = 1.0f / (1.0f + __expf(-to));

    float* crow = conf + (size_t)(b * PP + p) * NCLS;
    float smax = 0.0f;

    #pragma unroll
    for (int c0 = 0; c0 < NCLS; c0 += 4) {
        float v0 = 1.0f / (1.0f + __expf(-base[(5 + c0 + 0) * WH])) * so;
        float v1 = 1.0f / (1.0f + __expf(-base[(5 + c0 + 1) * WH])) * so;
        float v2 = 1.0f / (1.0f + __expf(-base[(5 + c0 + 2) * WH])) * so;
        float v3 = 1.0f / (1.0f + __expf(-base[(5 + c0 + 3) * WH])) * so;
        *reinterpret_cast<float4*>(crow + c0) = make_float4(v0, v1, v2, v3);
        smax = fmaxf(smax, fmaxf(fmaxf(v0, v1), fmaxf(v2, v3)));
    }

    scores[b * PP + p] = smax;
}

extern "C" void kernel_launch(void* const* d_in, const int* in_sizes, int n_in,
                              void* d_out, int out_size, void* d_ws, size_t ws_size,
                              hipStream_t stream) {
    const float* in      = (const float*)d_in[0];
    const float* anchors = (const float*)d_in[1];

    float* boxes  = (float*)d_out;                       // B*P*4  = 2,217,984
    float* conf   = boxes + (size_t)BB * PP * 4;         // B*P*80 = 44,359,680
    float* scores = conf + (size_t)BB * PP * NCLS;       // B*P    = 554,496

    int total  = BB * NA * WH;                           // 554,496
    int blocks = total / 256;                            // 2166 exactly
    yolo_decode_kernel<<<blocks, 256, 0, stream>>>(in, anchors, boxes, conf, scores);
}

// Round 2
// 108.149 us; speedup vs baseline: 1.8365x; 1.8365x over previous
//
#include <hip/hip_runtime.h>

// YOLO layer decode, MI355X.
// B=32, C=255=(5+80)*3, W=H=76.
// Outputs (concat flat in d_out): boxes (B,P,4), conf (B,P,80), scores (B,P)
// with P = W*H*3, p = (w*H+h)*3 + a.
//
// R2: register-buffer all 80 class loads (MLP), then back-to-back float4
// stores so each 64B conf line is completed within 4 consecutive store
// instructions (fixes 2.6x write amplification seen in R1 counters).

#define NCLS 80
#define NA   3
#define BB   32
#define WW   76
#define HH   76
#define WH   (WW*HH)          // 5776
#define PP   (WH*NA)          // 17328

__global__ __launch_bounds__(256) void yolo_decode_kernel(
    const float* __restrict__ in,       // (B, 255, W, H)
    const float* __restrict__ anchors,  // (2, 3) flat: [d*3 + a]
    float* __restrict__ boxes,          // (B, P, 4)
    float* __restrict__ conf,           // (B, P, 80)
    float* __restrict__ scores)         // (B, P)
{
    int idx = blockIdx.x * 256 + threadIdx.x;   // idx = (b*NA + a)*WH + s
    int s  = idx % WH;
    int ba = idx / WH;
    int a  = ba % NA;
    int b  = ba / NA;
    int w  = s / HH;
    int h  = s - w * HH;

    const float* base = in + (size_t)(b * 255 + a * 85) * WH + s;

    // ---- issue ALL loads first: 85 independent coalesced dword loads ----
    float tx = base[0];
    float ty = base[(size_t)1 * WH];
    float tw = base[(size_t)2 * WH];
    float th = base[(size_t)3 * WH];
    float to = base[(size_t)4 * WH];

    float t[NCLS];
    #pragma unroll
    for (int c = 0; c < NCLS; ++c)
        t[c] = base[(size_t)(5 + c) * WH];

    // ---- head math + box store ----
    float sx = 1.0f / (1.0f + __expf(-tx));
    float sy = 1.0f / (1.0f + __expf(-ty));
    float bx = (sx + (float)w) * (1.0f / WW);
    float by = (sy + (float)h) * (1.0f / HH);
    float bw = __expf(tw) * anchors[a];
    float bh = __expf(th) * anchors[3 + a];

    int p = s * 3 + a;

    float4 box = make_float4(bx - 0.5f * bw, by - 0.5f * bh,
                             bx + 0.5f * bw, by + 0.5f * bh);
    *reinterpret_cast<float4*>(boxes + (size_t)(b * PP + p) * 4) = box;

    float so = 1.0f / (1.0f + __expf(-to));

    // ---- conf: compute all 80 in registers, track max ----
    float smax = 0.0f;
    #pragma unroll
    for (int c = 0; c < NCLS; ++c) {
        float v = (1.0f / (1.0f + __expf(-t[c]))) * so;
        t[c] = v;
        smax = fmaxf(smax, v);
    }

    // ---- back-to-back stores: 20 float4 = 5 full 64B lines ----
    float* crow = conf + (size_t)(b * PP + p) * NCLS;
    #pragma unroll
    for (int c4 = 0; c4 < NCLS / 4; ++c4) {
        *reinterpret_cast<float4*>(crow + c4 * 4) =
            make_float4(t[4*c4+0], t[4*c4+1], t[4*c4+2], t[4*c4+3]);
    }

    scores[b * PP + p] = smax;
}

extern "C" void kernel_launch(void* const* d_in, const int* in_sizes, int n_in,
                              void* d_out, int out_size, void* d_ws, size_t ws_size,
                              hipStream_t stream) {
    const float* in      = (const float*)d_in[0];
    const float* anchors = (const float*)d_in[1];

    float* boxes  = (float*)d_out;                       // B*P*4  = 2,217,984
    float* conf   = boxes + (size_t)BB * PP * 4;         // B*P*80 = 44,359,680
    float* scores = conf + (size_t)BB * PP * NCLS;       // B*P    = 554,496

    int total  = BB * NA * WH;                           // 554,496
    int blocks = total / 256;                            // 2166 exactly
    yolo_decode_kernel<<<blocks, 256, 0, stream>>>(in, anchors, boxes, conf, scores);
}